// Round 1
// baseline (184.417 us; speedup 1.0000x reference)
//
#include <hip/hip_runtime.h>
#include <hip/hip_bf16.h>
#include <cstdint>

// AttentionHead: B=8, S=4096, E=768, H=64. fp32 in/out.
// Reference quirks: v = x@Wq.T (source bug), softmax over QUERY axis,
// scale = 1/sqrt(S)=1/64.
//
// Decomposition:
//   out[q,h] = sum_k exp(s[q,k]) * c[k] * v[k,h],  c[k] = 8 / sum_q exp(s[q,k])
// with Qb = bf16(Q/8), Kb = bf16(K/8) so s = dot(Qb_row, Kb_row) exactly,
// and V = Qb (the *8 in c compensates the /8 in V). |s| <~ 2 -> no max-sub.

#define BATCH 8
#define SEQ   4096
#define EMB   768
#define HD    64
#define NROW  (BATCH*SEQ)  // 32768

typedef float  f32x4  __attribute__((ext_vector_type(4)));
typedef __bf16 bf16x8 __attribute__((ext_vector_type(8)));
typedef unsigned short u16x8_t __attribute__((ext_vector_type(8)));
typedef unsigned short u16x4_t __attribute__((ext_vector_type(4)));

__device__ __forceinline__ f32x4 mfma16(bf16x8 a, bf16x8 b, f32x4 c) {
  return __builtin_amdgcn_mfma_f32_16x16x32_bf16(a, b, c, 0, 0, 0);
}
__device__ __forceinline__ unsigned short f2b(float f) {
  __bf16 h = (__bf16)f;  // RNE cvt; compiler fuses to v_cvt_pk where possible
  return __builtin_bit_cast(unsigned short, h);
}
__device__ __forceinline__ float b2f(unsigned short u) {
  unsigned int x = ((unsigned int)u) << 16;
  return __builtin_bit_cast(float, x);
}
// Row-major [R][64] bf16 tile, halfword index with G4 XOR swizzle
// (byte ^= (r&7)<<4 -> halfword: h ^ ((r&7)<<3)). 16B frag reads land
// 8 lanes per 16B slot -> conflict-free b128.
__device__ __forceinline__ int sidx(int r, int h) {
  return r * 64 + (h ^ ((r & 7) << 3));
}
// Transposed V tile [64 h][128 k] bf16. Two-term swizzle so both the
// b16 scatter WRITES (lanes vary h-chunk) and b128 frag READS (lanes
// vary h) spread across slots.
__device__ __forceinline__ int vidx(int h, int k) {
  return h * 128 + (k ^ ((((h & 7) ^ ((h >> 3) & 7))) << 3));
}
__device__ __forceinline__ bf16x8 ldsA(const unsigned short* p) {
  return __builtin_bit_cast(bf16x8, *(const u16x8_t*)p);
}

// ---------------- Kernel 1: projection GEMM ----------------
// Qb = bf16(X@Wq.T * 0.125), Kb = bf16(X@Wk.T * 0.125)
// M-tile 64 (512 blocks), N = 128 (Q cols 0-63 | K cols 64-127), K-chunk 64.
__global__ __launch_bounds__(256) void proj_kernel(
    const float* __restrict__ X, const float* __restrict__ Wq,
    const float* __restrict__ Wk, unsigned short* __restrict__ Qb,
    unsigned short* __restrict__ Kb) {
  __shared__ unsigned short Xs[64 * 64];
  __shared__ unsigned short Ws[128 * 64];
  const int t = threadIdx.x, lane = t & 63, wave = t >> 6;
  const int c = lane & 15, g = lane >> 4;
  const int row0 = blockIdx.x * 64;
  const f32x4 fzero = {0.f, 0.f, 0.f, 0.f};
  f32x4 acc[8];
#pragma unroll
  for (int f = 0; f < 8; ++f) acc[f] = fzero;

  for (int e0 = 0; e0 < EMB; e0 += 64) {
    __syncthreads();
#pragma unroll
    for (int j = 0; j < 4; ++j) {  // stage X[64][64] -> bf16
      int idx = t + 256 * j;
      int m = idx >> 4, c4 = idx & 15;
      float4 v = *(const float4*)(X + (size_t)(row0 + m) * EMB + e0 + 4 * c4);
      u16x4_t bv;
      bv[0] = f2b(v.x); bv[1] = f2b(v.y); bv[2] = f2b(v.z); bv[3] = f2b(v.w);
      *(u16x4_t*)(&Xs[sidx(m, 4 * c4)]) = bv;
    }
#pragma unroll
    for (int j = 0; j < 8; ++j) {  // stage W rows (Wq|Wk) -> bf16
      int idx = t + 256 * j;
      int n = idx >> 4, c4 = idx & 15;
      const float* src =
          (n < 64 ? Wq + (size_t)n * EMB : Wk + (size_t)(n - 64) * EMB) + e0 + 4 * c4;
      float4 v = *(const float4*)src;
      u16x4_t bv;
      bv[0] = f2b(v.x); bv[1] = f2b(v.y); bv[2] = f2b(v.z); bv[3] = f2b(v.w);
      *(u16x4_t*)(&Ws[sidx(n, 4 * c4)]) = bv;
    }
    __syncthreads();
    bf16x8 a0 = ldsA(&Xs[sidx(16 * wave + c, 8 * g)]);
    bf16x8 a1 = ldsA(&Xs[sidx(16 * wave + c, 32 + 8 * g)]);
#pragma unroll
    for (int f = 0; f < 8; ++f) {
      bf16x8 b0 = ldsA(&Ws[sidx(16 * f + c, 8 * g)]);
      bf16x8 b1 = ldsA(&Ws[sidx(16 * f + c, 32 + 8 * g)]);
      acc[f] = mfma16(a0, b0, acc[f]);
      acc[f] = mfma16(a1, b1, acc[f]);
    }
  }
#pragma unroll
  for (int f = 0; f < 8; ++f) {
    int n = 16 * f + c;
#pragma unroll
    for (int r = 0; r < 4; ++r) {
      int ROW = row0 + 16 * wave + 4 * g + r;
      unsigned short bv = f2b(acc[f][r] * 0.125f);
      if (n < 64) Qb[(size_t)ROW * 64 + n] = bv;
      else        Kb[(size_t)ROW * 64 + (n - 64)] = bv;
    }
  }
}

// ---------------- Kernel 2: column exp-sums ----------------
// Zpart[(b*4096+k)*4 + qs] = sum over 1024 q of exp(s[q,k]).
// grid (32 ktiles, 4 qsplits, 8 batches), 256 thr.
__global__ __launch_bounds__(256) void colsum_kernel(
    const unsigned short* __restrict__ Qb, const unsigned short* __restrict__ Kb,
    float* __restrict__ Zpart) {
  __shared__ unsigned short Ks[128 * 64];
  __shared__ unsigned short Qs[128 * 64];
  __shared__ float Zs[4][128];
  const int t = threadIdx.x, lane = t & 63, wave = t >> 6;
  const int c = lane & 15, g = lane >> 4;
  const int kt = blockIdx.x, qs = blockIdx.y, b = blockIdx.z;
  const size_t kbase = (size_t)b * SEQ + kt * 128;
  const f32x4 fzero = {0.f, 0.f, 0.f, 0.f};
#pragma unroll
  for (int j = 0; j < 4; ++j) {  // stage K tile once
    int idx = t + 256 * j;
    int kr = idx >> 3, ch = idx & 7;
    *(u16x8_t*)(&Ks[sidx(kr, 8 * ch)]) =
        *(const u16x8_t*)(Kb + (kbase + kr) * 64 + 8 * ch);
  }
  float csum[8] = {0.f, 0.f, 0.f, 0.f, 0.f, 0.f, 0.f, 0.f};
  for (int qi = 0; qi < 8; ++qi) {
    const size_t qbase = (size_t)b * SEQ + qs * 1024 + qi * 128;
    __syncthreads();
#pragma unroll
    for (int j = 0; j < 4; ++j) {
      int idx = t + 256 * j;
      int kr = idx >> 3, ch = idx & 7;
      *(u16x8_t*)(&Qs[sidx(kr, 8 * ch)]) =
          *(const u16x8_t*)(Qb + (qbase + kr) * 64 + 8 * ch);
    }
    __syncthreads();
    bf16x8 aq[2][2];
#pragma unroll
    for (int qf = 0; qf < 2; ++qf)
#pragma unroll
      for (int ks = 0; ks < 2; ++ks)
        aq[qf][ks] = ldsA(&Qs[sidx(32 * wave + 16 * qf + c, 32 * ks + 8 * g)]);
#pragma unroll
    for (int f = 0; f < 8; ++f) {
      bf16x8 b0 = ldsA(&Ks[sidx(16 * f + c, 8 * g)]);
      bf16x8 b1 = ldsA(&Ks[sidx(16 * f + c, 32 + 8 * g)]);
#pragma unroll
      for (int qf = 0; qf < 2; ++qf) {
        f32x4 s4 = mfma16(aq[qf][0], b0, fzero);
        s4 = mfma16(aq[qf][1], b1, s4);
        csum[f] += __expf(s4[0]) + __expf(s4[1]) + __expf(s4[2]) + __expf(s4[3]);
      }
    }
  }
#pragma unroll
  for (int f = 0; f < 8; ++f) {  // reduce over the 4 row-groups (g)
    float v = csum[f];
    v += __shfl_xor(v, 16);
    v += __shfl_xor(v, 32);
    if (lane < 16) Zs[wave][16 * f + lane] = v;
  }
  __syncthreads();
  if (t < 128)  // reduce over 4 waves (q-row groups), write partial
    Zpart[(kbase + t) * 4 + qs] = Zs[0][t] + Zs[1][t] + Zs[2][t] + Zs[3][t];
}

// ---------------- Kernel 3: c = 8 / Z ----------------
__global__ __launch_bounds__(256) void reduce_c_kernel(
    const float* __restrict__ Zpart, float* __restrict__ cv) {
  int i = blockIdx.x * 256 + threadIdx.x;
  if (i < NROW)
    cv[i] = 8.f / (Zpart[4 * i] + Zpart[4 * i + 1] + Zpart[4 * i + 2] + Zpart[4 * i + 3]);
}

// ---------------- Kernel 4: out = exp(QK^T/64) @ (c*V) ----------------
// grid (32 qtiles, 8 batches), 512 thr = 8 waves, q-tile 128 (16 rows/wave),
// k swept in 128-tiles. LDS = 16K (K) + 16K (Vt) + 32K (P) = 64 KB.
__global__ __launch_bounds__(512) void attn_kernel(
    const unsigned short* __restrict__ Qb, const unsigned short* __restrict__ Kb,
    const float* __restrict__ cv, float* __restrict__ Out) {
  __shared__ unsigned short Ks[128 * 64];
  __shared__ unsigned short Vt[64 * 128];
  __shared__ unsigned short Ps[8 * 16 * 128];
  const int t = threadIdx.x, lane = t & 63, wave = t >> 6;
  const int c = lane & 15, g = lane >> 4;
  const int q0 = blockIdx.x * 128, b = blockIdx.y;
  const size_t brow = (size_t)b * SEQ;
  const f32x4 fzero = {0.f, 0.f, 0.f, 0.f};

  bf16x8 aq[2];  // this wave's 16 Q rows, kept in registers for all k
#pragma unroll
  for (int ks = 0; ks < 2; ++ks)
    aq[ks] = __builtin_bit_cast(
        bf16x8, *(const u16x8_t*)(Qb + (brow + q0 + 16 * wave + c) * 64 + 32 * ks + 8 * g));

  f32x4 oa[4];
#pragma unroll
  for (int f = 0; f < 4; ++f) oa[f] = fzero;
  const int pbase = wave * 2048;

  for (int kt2 = 0; kt2 < 32; ++kt2) {
    const size_t kbase = brow + kt2 * 128;
    __syncthreads();
#pragma unroll
    for (int j = 0; j < 2; ++j) {  // stage K tile (row-major, swizzled)
      int idx = t + 512 * j;
      int kr = idx >> 3, ch = idx & 7;
      *(u16x8_t*)(&Ks[sidx(kr, 8 * ch)]) =
          *(const u16x8_t*)(Kb + (kbase + kr) * 64 + 8 * ch);
    }
#pragma unroll
    for (int j = 0; j < 2; ++j) {  // stage Vt = transpose(c[k] * Qb[ktile])
      int idx = t + 512 * j;
      int kr = idx >> 3, ch = idx & 7;
      u16x8_t v8 = *(const u16x8_t*)(Qb + (kbase + kr) * 64 + 8 * ch);
      float s = cv[kbase + kr];
#pragma unroll
      for (int i = 0; i < 8; ++i) {
        int h = 8 * ch + i;
        Vt[vidx(h, kr)] = f2b(s * b2f(v8[i]));
      }
    }
    __syncthreads();
    // S = QK^T (per-wave 16q x 128k), exp, park in per-wave P region
#pragma unroll
    for (int f = 0; f < 8; ++f) {
      bf16x8 b0 = ldsA(&Ks[sidx(16 * f + c, 8 * g)]);
      bf16x8 b1 = ldsA(&Ks[sidx(16 * f + c, 32 + 8 * g)]);
      f32x4 s4 = mfma16(aq[0], b0, fzero);
      s4 = mfma16(aq[1], b1, s4);
#pragma unroll
      for (int r = 0; r < 4; ++r) {
        int q = 4 * g + r;
        Ps[pbase + q * 128 + ((16 * f + c) ^ ((q & 7) << 3))] = f2b(__expf(s4[r]));
      }
    }
    // PV: oa[16q x 64h] += P[16q x 128k] * Vt
#pragma unroll
    for (int ks = 0; ks < 4; ++ks) {
      bf16x8 pa = ldsA(&Ps[pbase + c * 128 + ((32 * ks + 8 * g) ^ ((c & 7) << 3))]);
#pragma unroll
      for (int fp = 0; fp < 4; ++fp) {
        bf16x8 bv = ldsA(&Vt[vidx(16 * fp + c, 32 * ks + 8 * g)]);
        oa[fp] = mfma16(pa, bv, oa[fp]);
      }
    }
  }
#pragma unroll
  for (int fp = 0; fp < 4; ++fp)
#pragma unroll
    for (int r = 0; r < 4; ++r) {
      int q = q0 + 16 * wave + 4 * g + r;
      Out[(brow + q) * 64 + 16 * fp + c] = oa[fp][r];
    }
}

extern "C" void kernel_launch(void* const* d_in, const int* in_sizes, int n_in,
                              void* d_out, int out_size, void* d_ws, size_t ws_size,
                              hipStream_t stream) {
  const float* X  = (const float*)d_in[0];
  const float* Wq = (const float*)d_in[1];
  const float* Wk = (const float*)d_in[2];
  // d_in[3] (Wv) is unused: reference computes v with q_net.
  float* Out = (float*)d_out;

  unsigned char* w = (unsigned char*)d_ws;
  unsigned short* Qb = (unsigned short*)w;                          // 4 MB
  unsigned short* Kb = (unsigned short*)(w + (size_t)NROW * 64 * 2);  // 4 MB
  float* Zpart = (float*)(w + (size_t)NROW * 64 * 4);              // 512 KB
  float* cv    = (float*)(w + (size_t)NROW * 64 * 4 + (size_t)NROW * 4 * 4);

  hipLaunchKernelGGL(proj_kernel, dim3(NROW / 64), dim3(256), 0, stream,
                     X, Wq, Wk, Qb, Kb);
  hipLaunchKernelGGL(colsum_kernel, dim3(32, 4, 8), dim3(256), 0, stream,
                     Qb, Kb, Zpart);
  hipLaunchKernelGGL(reduce_c_kernel, dim3(128), dim3(256), 0, stream, Zpart, cv);
  hipLaunchKernelGGL(attn_kernel, dim3(32, 8), dim3(512), 0, stream,
                     Qb, Kb, cv, Out);
}

// Round 2
// 110.226 us; speedup vs baseline: 1.6731x; 1.6731x over previous
//
#include <hip/hip_runtime.h>
#include <hip/hip_bf16.h>
#include <cstdint>

// AttentionHead: B=8, S=4096, E=768, H=64. fp32 in/out.
// Reference quirks: v = x@Wq.T (source bug), softmax over QUERY axis,
// scale = 1/sqrt(S) = 1/64.
//
// out[q,h] = sum_k exp(s[q,k]) * v[k,h] / Z[k],  Z[k] = sum_q exp(s[q,k])
// Qb = bf16(q * 0.125*log2e), Kb = bf16(k * 0.125)  =>  dot(Qb,Kb) = log2e*s
// P = exp2(dot) = e^s. VT[h,k] = cv[k]*Qb[k,h], cv = (1/0.18034)/Z[k].
// |s| <= ~1 -> no max subtraction needed.

#define BATCH 8
#define SEQ   4096
#define EMB   768
#define HD    64
#define NROW  (BATCH*SEQ)  // 32768

#define QSCALE 0.1803368801111201f   // 0.125 * log2(e)
#define KSCALE 0.125f
#define CSCALE 5.545177444479562f    // 1 / QSCALE

typedef float  f32x4  __attribute__((ext_vector_type(4)));
typedef float  f32x16 __attribute__((ext_vector_type(16)));
typedef __bf16 bf16x8 __attribute__((ext_vector_type(8)));
typedef unsigned short u16x8_t __attribute__((ext_vector_type(8)));
typedef unsigned int   u32x4_t __attribute__((ext_vector_type(4)));

__device__ __forceinline__ f32x4 mfma16(bf16x8 a, bf16x8 b, f32x4 c) {
  return __builtin_amdgcn_mfma_f32_16x16x32_bf16(a, b, c, 0, 0, 0);
}
__device__ __forceinline__ f32x16 mfma32(bf16x8 a, bf16x8 b, f32x16 c) {
  return __builtin_amdgcn_mfma_f32_32x32x16_bf16(a, b, c, 0, 0, 0);
}
__device__ __forceinline__ unsigned short f2b(float f) {
  __bf16 h = (__bf16)f;
  return __builtin_bit_cast(unsigned short, h);
}
__device__ __forceinline__ float b2f(unsigned short u) {
  unsigned int x = ((unsigned int)u) << 16;
  return __builtin_bit_cast(float, x);
}
__device__ __forceinline__ bf16x8 ldsA(const unsigned short* p) {
  return __builtin_bit_cast(bf16x8, *(const u16x8_t*)p);
}
__device__ __forceinline__ float expf2(float x) {  // 2^x, |x| small
  float r; asm("v_exp_f32 %0, %1" : "=v"(r) : "v"(x)); return r;
}
__device__ __forceinline__ unsigned cvtpk(float lo, float hi) {  // pack 2 f32 -> 2 bf16
  unsigned r; asm("v_cvt_pk_bf16_f32 %0, %1, %2" : "=v"(r) : "v"(lo), "v"(hi)); return r;
}
__device__ __forceinline__ void plane32swap(unsigned &a, unsigned &b) {
  // swap a's lanes 32-63 with b's lanes 0-31
  asm volatile("v_permlane32_swap_b32 %0, %1" : "+v"(a), "+v"(b));
}
__device__ __forceinline__ void glld16(const void* g, void* l) {
  // 16B/lane global->LDS; LDS dest = wave-uniform base + lane*16
  __builtin_amdgcn_global_load_lds(
      (const __attribute__((address_space(1))) void*)g,
      (__attribute__((address_space(3))) void*)l, 16, 0, 0);
}
// G4 XOR swizzle for row-major [R][64] bf16 tiles (halfword index)
__device__ __forceinline__ int sidx(int r, int h) {
  return r * 64 + (h ^ ((r & 7) << 3));
}

// ---------------- Kernel 0: W -> bf16 (Wq rows 0-63 | Wk rows 64-127) ----
__global__ __launch_bounds__(256) void wcvt_kernel(
    const float* __restrict__ Wq, const float* __restrict__ Wk,
    unsigned short* __restrict__ Wb) {
  int ci = blockIdx.x * 256 + threadIdx.x;  // 12288 chunks of 8
  int r = ci / 96, c8 = ci % 96;
  const float* src = (r < 64 ? Wq + (size_t)r * EMB : Wk + (size_t)(r - 64) * EMB) + c8 * 8;
  float4 a = *(const float4*)src, d = *(const float4*)(src + 4);
  u16x8_t o;
  o[0]=f2b(a.x); o[1]=f2b(a.y); o[2]=f2b(a.z); o[3]=f2b(a.w);
  o[4]=f2b(d.x); o[5]=f2b(d.y); o[6]=f2b(d.z); o[7]=f2b(d.w);
  *(u16x8_t*)(Wb + (size_t)ci * 8) = o;
}

// ---------------- Kernel 1: projection GEMM ----------------
// Qb = bf16(X@Wq.T * QSCALE), Kb = bf16(X@Wk.T * KSCALE). M-tile 64, 512 blocks.
// X loaded direct global->frag (wave-private rows); W-bf16 LDS-staged, dbuf.
__global__ __launch_bounds__(256) void proj_kernel(
    const float* __restrict__ X, const unsigned short* __restrict__ Wb,
    unsigned short* __restrict__ Qb, unsigned short* __restrict__ Kb) {
  __shared__ unsigned short Ws[2][8192];
  const int t = threadIdx.x, lane = t & 63, w = t >> 6;
  const int c = lane & 15, g = lane >> 4;
  const int row0 = blockIdx.x * 64;
  f32x4 acc[8];
#pragma unroll
  for (int f = 0; f < 8; ++f) { acc[f][0]=0.f; acc[f][1]=0.f; acc[f][2]=0.f; acc[f][3]=0.f; }

  auto STAGE = [&](int ec, int bb) {
#pragma unroll
    for (int i = 0; i < 4; ++i) {
      int rr = w + 4 * i;               // uniform per wave
      int ci = rr * 64 + lane;
      int r = ci >> 3, cL = ci & 7;
      glld16(Wb + (size_t)r * EMB + ec * 64 + (cL ^ (r & 7)) * 8, (void*)&Ws[bb][rr * 512]);
    }
  };
  STAGE(0, 0);
  __syncthreads();
  for (int ec = 0; ec < 12; ++ec) {
    if (ec < 11) STAGE(ec + 1, (ec + 1) & 1);
    bf16x8 Af[2];
#pragma unroll
    for (int es = 0; es < 2; ++es) {
      const float* xp = X + (size_t)(row0 + 16 * w + c) * EMB + ec * 64 + es * 32 + 8 * g;
      float4 v0 = *(const float4*)xp, v1 = *(const float4*)(xp + 4);
      u16x8_t tmp;
      tmp[0]=f2b(v0.x); tmp[1]=f2b(v0.y); tmp[2]=f2b(v0.z); tmp[3]=f2b(v0.w);
      tmp[4]=f2b(v1.x); tmp[5]=f2b(v1.y); tmp[6]=f2b(v1.z); tmp[7]=f2b(v1.w);
      Af[es] = __builtin_bit_cast(bf16x8, tmp);
    }
    const unsigned short* Wt = Ws[ec & 1];
#pragma unroll
    for (int es = 0; es < 2; ++es)
#pragma unroll
      for (int f = 0; f < 8; ++f) {
        bf16x8 Bf = ldsA(&Wt[sidx(16 * f + c, es * 32 + 8 * g)]);
        acc[f] = mfma16(Af[es], Bf, acc[f]);
      }
    __syncthreads();
  }
#pragma unroll
  for (int f = 0; f < 8; ++f) {
    int n = 16 * f + c;
    float sc = (n < 64) ? QSCALE : KSCALE;
#pragma unroll
    for (int r = 0; r < 4; ++r) {
      int ROW = row0 + 16 * w + 4 * g + r;
      unsigned short bv = f2b(acc[f][r] * sc);
      if (n < 64) Qb[(size_t)ROW * 64 + n] = bv;
      else        Kb[(size_t)ROW * 64 + (n - 64)] = bv;
    }
  }
}

// ---------------- Kernel 2: column exp2-sums ----------------
// Zpart[k*4+qs] = sum over 1024 q of exp2(dot). K-frags persistent in regs;
// Q staged in LDS (shared by 4 waves), 2-phase dbuf. D[q][k]: col = own k.
__global__ __launch_bounds__(256) void colsum_kernel(
    const unsigned short* __restrict__ Qb, const unsigned short* __restrict__ Kb,
    float* __restrict__ Zpart) {
  __shared__ unsigned short Qs[2][8192];
  const int t = threadIdx.x, lane = t & 63, w = t >> 6;
  const int c = lane & 31, hi = lane >> 5;
  int fid = blockIdx.x + 32 * (blockIdx.y + 4 * blockIdx.z);
  int s = (fid & 7) * 128 + (fid >> 3);          // XCD-chunked swizzle (1024%8==0)
  const int kt = s & 31, qs = (s >> 5) & 3, b = s >> 7;
  const size_t kbase = (size_t)b * SEQ + kt * 128;
  const size_t qbase0 = (size_t)b * SEQ + qs * 1024;

  bf16x8 Kf[4];  // own 32 k-rows (n-operand), e = 16*es + 8*hi + i
#pragma unroll
  for (int es = 0; es < 4; ++es)
    Kf[es] = __builtin_bit_cast(bf16x8,
        *(const u16x8_t*)(Kb + (kbase + 32 * w + c) * 64 + 16 * es + 8 * hi));

  auto STAGE = [&](int qi, int bb) {
#pragma unroll
    for (int i = 0; i < 4; ++i) {
      int rr = w + 4 * i;
      int ci = rr * 64 + lane;
      int r = ci >> 3, cL = ci & 7;
      glld16(Qb + (qbase0 + qi * 128 + r) * 64 + (cL ^ (r & 7)) * 8, (void*)&Qs[bb][rr * 512]);
    }
  };
  float csum = 0.f;
  STAGE(0, 0);
  __syncthreads();
  for (int qi = 0; qi < 8; ++qi) {
    if (qi < 7) STAGE(qi + 1, (qi + 1) & 1);
    const unsigned short* Qt = Qs[qi & 1];
#pragma unroll
    for (int sq = 0; sq < 4; ++sq) {
      f32x16 sv;
#pragma unroll
      for (int i = 0; i < 16; ++i) sv[i] = 0.f;
#pragma unroll
      for (int es = 0; es < 4; ++es) {
        bf16x8 A = ldsA(&Qt[sidx(32 * sq + c, 16 * es + 8 * hi)]);  // m = q-row
        sv = mfma32(A, Kf[es], sv);
      }
#pragma unroll
      for (int i = 0; i < 16; ++i) csum += expf2(sv[i]);
    }
    __syncthreads();
  }
  csum += __shfl_xor(csum, 32);  // merge hi row-halves
  if (lane < 32)
    Zpart[(kbase + 32 * w + lane) * 4 + qs] = csum;
}

// ---------------- Kernel 3: cv = CSCALE / Z ----------------
__global__ __launch_bounds__(256) void reduce_c_kernel(
    const float* __restrict__ Zpart, float* __restrict__ cv) {
  int i = blockIdx.x * 256 + threadIdx.x;
  if (i < NROW)
    cv[i] = CSCALE / (Zpart[4*i] + Zpart[4*i+1] + Zpart[4*i+2] + Zpart[4*i+3]);
}

// ---------------- Kernel 4: VT[b][h][k] = cv[k] * Qb[k][h] ----------------
__global__ __launch_bounds__(256) void vtrans_kernel(
    const unsigned short* __restrict__ Qb, const float* __restrict__ cv,
    unsigned short* __restrict__ VT) {
  __shared__ unsigned short T[128 * 72];
  __shared__ float cvs[128];
  const int t = threadIdx.x;
  const int kt = blockIdx.x, b = blockIdx.y;
  const size_t kbase = (size_t)b * SEQ + kt * 128;
#pragma unroll
  for (int it = 0; it < 4; ++it) {  // stage 128x64 tile, chunk-swizzled by r>>3
    int ci = t + 256 * it;
    int r = ci >> 3, ch = ci & 7;
    u16x8_t v = *(const u16x8_t*)(Qb + (kbase + r) * 64 + 8 * ch);
    *(u16x8_t*)(&T[r * 72 + 8 * (ch ^ ((r >> 3) & 7))]) = v;
  }
  if (t < 128) cvs[t] = cv[kbase + t];
  __syncthreads();
#pragma unroll
  for (int it = 0; it < 4; ++it) {
    int ci = t + 256 * it;
    int h = ci >> 4, c16 = ci & 15;
    u16x8_t o;
#pragma unroll
    for (int j = 0; j < 8; ++j) {
      int r = 8 * c16 + j;
      unsigned short raw = T[r * 72 + 8 * ((h >> 3) ^ (c16 & 7)) + (h & 7)];
      o[j] = f2b(cvs[r] * b2f(raw));
    }
    *(u16x8_t*)(VT + ((size_t)(b * 64 + h)) * SEQ + kt * 128 + 8 * c16) = o;
  }
}

// ---------------- Kernel 5: attention ----------------
// 256 thr (4 waves), q-block 128 (32 q/wave), k swept in 128-tiles.
// Swapped QK (A=K, B=Q) -> P column per lane; cvt_pk + permlane32_swap builds
// PV A-frags in-register. K/V staged via global_load_lds (pre-swizzled src),
// double-buffered; LDS 64KB -> 2 blocks/CU.
__global__ __launch_bounds__(256) void attn_kernel(
    const unsigned short* __restrict__ Qb, const unsigned short* __restrict__ Kb,
    const unsigned short* __restrict__ VT, float* __restrict__ outp, int nkt) {
  __shared__ unsigned short KV[2][16384];  // [buf][K 8192 | V 8192]
  const int t = threadIdx.x, lane = t & 63, w = t >> 6;
  const int c = lane & 31, hi = lane >> 5;
  int fid = blockIdx.x + 32 * (blockIdx.y + gridDim.y * blockIdx.z);
  int qt, ks, b;
  if (gridDim.y == 2) {  // XCD-chunked swizzle (512%8==0): XCD x gets batch x
    int s = (fid & 7) * 64 + (fid >> 3);
    qt = s & 31; ks = (s >> 5) & 1; b = s >> 6;
  } else { qt = blockIdx.x; ks = 0; b = blockIdx.z; }
  const size_t brow = (size_t)b * SEQ;
  const int q0 = qt * 128;
  const int koff = ks * nkt;  // k-tile offset

  bf16x8 Qf[4];  // persistent B-frags: n = own q row, e = 16*es + 8*hi + i
#pragma unroll
  for (int es = 0; es < 4; ++es)
    Qf[es] = __builtin_bit_cast(bf16x8,
        *(const u16x8_t*)(Qb + (brow + q0 + 32 * w + c) * 64 + 16 * es + 8 * hi));

  f32x16 acc0, acc1;
#pragma unroll
  for (int i = 0; i < 16; ++i) { acc0[i] = 0.f; acc1[i] = 0.f; }

  auto STAGE = [&](int tt, int bb) {
    const size_t kb0 = brow + (size_t)(koff + tt) * 128;
#pragma unroll
    for (int i = 0; i < 8; ++i) {
      int rr = w + 4 * i;  // uniform per wave; rr<16: K, else V
      int ci = rr * 64 + lane;
      if (rr < 16) {
        int r = ci >> 3, cL = ci & 7;
        glld16(Kb + (kb0 + r) * 64 + (cL ^ (r & 7)) * 8, (void*)&KV[bb][rr * 512]);
      } else {
        int j = ci - 1024;
        int h = j >> 4, cL = j & 15;
        glld16(VT + ((size_t)(b * 64 + h)) * SEQ + (size_t)(koff + tt) * 128 +
                   (cL ^ (h & 7)) * 8,
               (void*)&KV[bb][rr * 512]);
      }
    }
  };

  auto COMPUTE = [&](int bb) {
    const unsigned short* Ks = &KV[bb][0];
    const unsigned short* Vs = &KV[bb][8192];
#pragma unroll
    for (int kb = 0; kb < 4; ++kb) {
      // QK^T swapped: D[k-row][q-col], col = own q
      f32x16 sv;
#pragma unroll
      for (int i = 0; i < 16; ++i) sv[i] = 0.f;
#pragma unroll
      for (int es = 0; es < 4; ++es) {
        bf16x8 KA = ldsA(&Ks[sidx(32 * kb + c, 16 * es + 8 * hi)]);
        sv = mfma32(KA, Qf[es], sv);
      }
      float p[16];
#pragma unroll
      for (int i = 0; i < 16; ++i) p[i] = expf2(sv[i]);
      // m214-v22: regs 0-7 -> k-rows 0..15 (after swap), 8-15 -> 16..31
      unsigned X0 = cvtpk(p[0], p[1]),  X1 = cvtpk(p[2], p[3]);
      unsigned Y0 = cvtpk(p[4], p[5]),  Y1 = cvtpk(p[6], p[7]);
      plane32swap(X0, Y0); plane32swap(X1, Y1);
      u32x4_t F0 = {X0, X1, Y0, Y1};
      unsigned Z0 = cvtpk(p[8], p[9]),  Z1 = cvtpk(p[10], p[11]);
      unsigned W0 = cvtpk(p[12], p[13]), W1 = cvtpk(p[14], p[15]);
      plane32swap(Z0, W0); plane32swap(Z1, W1);
      u32x4_t F1 = {Z0, Z1, W0, W1};
      bf16x8 fA0 = __builtin_bit_cast(bf16x8, F0);
      bf16x8 fA1 = __builtin_bit_cast(bf16x8, F1);
      // PV: acc[q][h] += P * V'
#pragma unroll
      for (int hb = 0; hb < 2; ++hb) {
        int h = 32 * hb + c;
        int col0 = 32 * kb + 8 * hi;
        bf16x8 VB0 = ldsA(&Vs[h * 128 + (col0 ^ ((h & 7) << 3))]);
        bf16x8 VB1 = ldsA(&Vs[h * 128 + ((col0 + 16) ^ ((h & 7) << 3))]);
        if (hb == 0) { acc0 = mfma32(fA0, VB0, acc0); acc0 = mfma32(fA1, VB1, acc0); }
        else         { acc1 = mfma32(fA0, VB0, acc1); acc1 = mfma32(fA1, VB1, acc1); }
      }
    }
  };

  STAGE(0, 0);
  __syncthreads();
  for (int tt = 0; tt < nkt; ++tt) {
    if (tt + 1 < nkt) STAGE(tt + 1, (tt + 1) & 1);
    COMPUTE(tt & 1);
    __syncthreads();
  }
  float* op = outp + (size_t)ks * NROW * 64;
#pragma unroll
  for (int hb = 0; hb < 2; ++hb)
#pragma unroll
    for (int r = 0; r < 16; ++r) {
      int qrow = (r & 3) + 8 * (r >> 2) + 4 * hi;
      float v = hb ? acc1[r] : acc0[r];
      op[(brow + q0 + 32 * w + qrow) * 64 + 32 * hb + c] = v;
    }
}

// ---------------- Kernel 6: combine k-split partials ----------------
__global__ __launch_bounds__(256) void osum_kernel(
    const float4* __restrict__ A, const float4* __restrict__ B,
    float4* __restrict__ O) {
  int i = blockIdx.x * 256 + threadIdx.x;
  float4 x = A[i], y = B[i];
  float4 o; o.x = x.x + y.x; o.y = x.y + y.y; o.z = x.z + y.z; o.w = x.w + y.w;
  O[i] = o;
}

extern "C" void kernel_launch(void* const* d_in, const int* in_sizes, int n_in,
                              void* d_out, int out_size, void* d_ws, size_t ws_size,
                              hipStream_t stream) {
  const float* X  = (const float*)d_in[0];
  const float* Wq = (const float*)d_in[1];
  const float* Wk = (const float*)d_in[2];
  // d_in[3] (Wv) unused: reference computes v with q_net.
  float* Out = (float*)d_out;

  unsigned char* wsb = (unsigned char*)d_ws;
  const size_t QB_OFF = 0;                    // 4 MB bf16
  const size_t KB_OFF = 4194304;              // 4 MB bf16
  const size_t WB_OFF = 8388608;              // 192 KB bf16
  const size_t Z_OFF  = 8585216;              // 512 KB f32
  const size_t CV_OFF = 9109504;              // 128 KB f32
  const size_t VT_OFF = 9240576;              // 4 MB bf16
  const size_t OP_OFF = 13434880;             // 16 MB f32 (split only)
  const size_t TOTAL_SPLIT = 30212096;

  unsigned short* Qb = (unsigned short*)(wsb + QB_OFF);
  unsigned short* Kb = (unsigned short*)(wsb + KB_OFF);
  unsigned short* Wb = (unsigned short*)(wsb + WB_OFF);
  float* Zpart       = (float*)(wsb + Z_OFF);
  float* cv          = (float*)(wsb + CV_OFF);
  unsigned short* VT = (unsigned short*)(wsb + VT_OFF);
  float* Opart       = (float*)(wsb + OP_OFF);

  const bool split = (ws_size >= TOTAL_SPLIT);

  hipLaunchKernelGGL(wcvt_kernel, dim3(48), dim3(256), 0, stream, Wq, Wk, Wb);
  hipLaunchKernelGGL(proj_kernel, dim3(NROW / 64), dim3(256), 0, stream, X, Wb, Qb, Kb);
  hipLaunchKernelGGL(colsum_kernel, dim3(32, 4, 8), dim3(256), 0, stream, Qb, Kb, Zpart);
  hipLaunchKernelGGL(reduce_c_kernel, dim3(128), dim3(256), 0, stream, Zpart, cv);
  hipLaunchKernelGGL(vtrans_kernel, dim3(32, 8), dim3(256), 0, stream, Qb, cv, VT);
  if (split) {
    hipLaunchKernelGGL(attn_kernel, dim3(32, 2, 8), dim3(256), 0, stream,
                       Qb, Kb, VT, Opart, 16);
    hipLaunchKernelGGL(osum_kernel, dim3(2048), dim3(256), 0, stream,
                       (const float4*)Opart, (const float4*)(Opart + (size_t)NROW * 64),
                       (float4*)Out);
  } else {
    hipLaunchKernelGGL(attn_kernel, dim3(32, 1, 8), dim3(256), 0, stream,
                       Qb, Kb, VT, Out, 32);
  }
}

// Round 3
// 105.540 us; speedup vs baseline: 1.7474x; 1.0444x over previous
//
#include <hip/hip_runtime.h>
#include <hip/hip_bf16.h>
#include <cstdint>

// AttentionHead: B=8, S=4096, E=768, H=64. fp32 in/out.
// Reference quirks: v = x@Wq.T (source bug), softmax over QUERY axis,
// scale = 1/sqrt(S) = 1/64.
//
// out[q,h] = sum_k exp(s[q,k]) * v[k,h] / Z[k],  Z[k] = sum_q exp(s[q,k])
// Qb = bf16(q * 0.125*log2e), Kb = bf16(k * 0.125)  =>  dot(Qb,Kb) = log2e*s
// P = exp2(dot) = e^s. VT[h,k] = cv[k]*Qb[k,h], cv = CSCALE/Z[k].
// |s| <= ~1 -> no max subtraction needed.

#define BATCH 8
#define SEQ   4096
#define EMB   768
#define HD    64
#define NROW  (BATCH*SEQ)  // 32768

#define QSCALE 0.1803368801111201f   // 0.125 * log2(e)
#define KSCALE 0.125f
#define CSCALE 5.545177444479562f    // 1 / QSCALE

typedef float  f32x4  __attribute__((ext_vector_type(4)));
typedef float  f32x16 __attribute__((ext_vector_type(16)));
typedef __bf16 bf16x8 __attribute__((ext_vector_type(8)));
typedef unsigned short u16x8_t __attribute__((ext_vector_type(8)));
typedef unsigned int   u32x4_t __attribute__((ext_vector_type(4)));

__device__ __forceinline__ f32x4 mfma16(bf16x8 a, bf16x8 b, f32x4 c) {
  return __builtin_amdgcn_mfma_f32_16x16x32_bf16(a, b, c, 0, 0, 0);
}
__device__ __forceinline__ f32x16 mfma32(bf16x8 a, bf16x8 b, f32x16 c) {
  return __builtin_amdgcn_mfma_f32_32x32x16_bf16(a, b, c, 0, 0, 0);
}
__device__ __forceinline__ unsigned short f2b(float f) {
  __bf16 h = (__bf16)f;
  return __builtin_bit_cast(unsigned short, h);
}
__device__ __forceinline__ float b2f(unsigned short u) {
  unsigned int x = ((unsigned int)u) << 16;
  return __builtin_bit_cast(float, x);
}
__device__ __forceinline__ bf16x8 ldsA(const unsigned short* p) {
  return __builtin_bit_cast(bf16x8, *(const u16x8_t*)p);
}
__device__ __forceinline__ float expf2(float x) {  // 2^x
  float r; asm("v_exp_f32 %0, %1" : "=v"(r) : "v"(x)); return r;
}
__device__ __forceinline__ unsigned cvtpk(float lo, float hi) {  // 2 f32 -> 2 bf16
  unsigned r; asm("v_cvt_pk_bf16_f32 %0, %1, %2" : "=v"(r) : "v"(lo), "v"(hi)); return r;
}
__device__ __forceinline__ void plane32swap(unsigned &a, unsigned &b) {
  asm volatile("v_permlane32_swap_b32 %0, %1" : "+v"(a), "+v"(b));
}
__device__ __forceinline__ void glld16(const void* g, void* l) {
  __builtin_amdgcn_global_load_lds(
      (const __attribute__((address_space(1))) void*)g,
      (__attribute__((address_space(3))) void*)l, 16, 0, 0);
}
// G4 XOR swizzle for row-major [R][64] bf16 tiles (halfword index)
__device__ __forceinline__ int sidx(int r, int h) {
  return r * 64 + (h ^ ((r & 7) << 3));
}

// ---------------- Kernel 0: W -> bf16 (Wq rows 0-63 | Wk rows 64-127) ----
__global__ __launch_bounds__(256) void wcvt_kernel(
    const float* __restrict__ Wq, const float* __restrict__ Wk,
    unsigned short* __restrict__ Wb) {
  int ci = blockIdx.x * 256 + threadIdx.x;  // 12288 chunks of 8
  int r = ci / 96, c8 = ci % 96;
  const float* src = (r < 64 ? Wq + (size_t)r * EMB : Wk + (size_t)(r - 64) * EMB) + c8 * 8;
  float4 a = *(const float4*)src, d = *(const float4*)(src + 4);
  u16x8_t o;
  o[0]=f2b(a.x); o[1]=f2b(a.y); o[2]=f2b(a.z); o[3]=f2b(a.w);
  o[4]=f2b(d.x); o[5]=f2b(d.y); o[6]=f2b(d.z); o[7]=f2b(d.w);
  *(u16x8_t*)(Wb + (size_t)ci * 8) = o;
}

// ---------------- Kernel 1: projection GEMM ----------------
// Qb = bf16(X@Wq.T * QSCALE), Kb = bf16(X@Wk.T * KSCALE). M-tile 64, 512 blocks.
__global__ __launch_bounds__(256) void proj_kernel(
    const float* __restrict__ X, const unsigned short* __restrict__ Wb,
    unsigned short* __restrict__ Qb, unsigned short* __restrict__ Kb) {
  __shared__ unsigned short Ws[2][8192];
  const int t = threadIdx.x, lane = t & 63, w = t >> 6;
  const int c = lane & 15, g = lane >> 4;
  const int row0 = blockIdx.x * 64;
  f32x4 acc[8];
#pragma unroll
  for (int f = 0; f < 8; ++f) { acc[f][0]=0.f; acc[f][1]=0.f; acc[f][2]=0.f; acc[f][3]=0.f; }

  auto STAGE = [&](int ec, int bb) {
#pragma unroll
    for (int i = 0; i < 4; ++i) {
      int rr = w + 4 * i;               // uniform per wave
      int ci = rr * 64 + lane;
      int r = ci >> 3, cL = ci & 7;
      glld16(Wb + (size_t)r * EMB + ec * 64 + (cL ^ (r & 7)) * 8, (void*)&Ws[bb][rr * 512]);
    }
  };
  STAGE(0, 0);
  __syncthreads();
  for (int ec = 0; ec < 12; ++ec) {
    if (ec < 11) STAGE(ec + 1, (ec + 1) & 1);
    bf16x8 Af[2];
#pragma unroll
    for (int es = 0; es < 2; ++es) {
      const float* xp = X + (size_t)(row0 + 16 * w + c) * EMB + ec * 64 + es * 32 + 8 * g;
      float4 v0 = *(const float4*)xp, v1 = *(const float4*)(xp + 4);
      u16x8_t tmp;
      tmp[0]=f2b(v0.x); tmp[1]=f2b(v0.y); tmp[2]=f2b(v0.z); tmp[3]=f2b(v0.w);
      tmp[4]=f2b(v1.x); tmp[5]=f2b(v1.y); tmp[6]=f2b(v1.z); tmp[7]=f2b(v1.w);
      Af[es] = __builtin_bit_cast(bf16x8, tmp);
    }
    const unsigned short* Wt = Ws[ec & 1];
#pragma unroll
    for (int es = 0; es < 2; ++es)
#pragma unroll
      for (int f = 0; f < 8; ++f) {
        bf16x8 Bf = ldsA(&Wt[sidx(16 * f + c, es * 32 + 8 * g)]);
        acc[f] = mfma16(Af[es], Bf, acc[f]);
      }
    __syncthreads();
  }
#pragma unroll
  for (int f = 0; f < 8; ++f) {
    int n = 16 * f + c;
    float sc = (n < 64) ? QSCALE : KSCALE;
#pragma unroll
    for (int r = 0; r < 4; ++r) {
      int ROW = row0 + 16 * w + 4 * g + r;
      unsigned short bv = f2b(acc[f][r] * sc);
      if (n < 64) Qb[(size_t)ROW * 64 + n] = bv;
      else        Kb[(size_t)ROW * 64 + (n - 64)] = bv;
    }
  }
}

// ---------------- Kernel 2: column exp2-sums ----------------
// 64 k/wave (2 k-blocks), K-frags persistent; Q staged LDS dbuf, A-frags
// read once and reused for both k-blocks -> 64 FLOP/LDS-byte.
// grid 512 = 16 kt x 4 qs x 8 b, XCD-chunked (b = fid&7).
__global__ __launch_bounds__(256) void colsum_kernel(
    const unsigned short* __restrict__ Qb, const unsigned short* __restrict__ Kb,
    float* __restrict__ Zpart) {
  __shared__ unsigned short Qs[2][8192];
  const int t = threadIdx.x, lane = t & 63, w = t >> 6;
  const int c = lane & 31, hi = lane >> 5;
  const int fid = blockIdx.x;
  const int b = fid & 7, rem = fid >> 3;
  const int kt = rem & 15, qs = rem >> 4;
  const size_t kbase = (size_t)b * SEQ + kt * 256;
  const size_t qbase0 = (size_t)b * SEQ + qs * 1024;

  bf16x8 Kf[2][4];  // own 64 k-rows: kbase + 64w + 32j + c
#pragma unroll
  for (int j = 0; j < 2; ++j)
#pragma unroll
    for (int es = 0; es < 4; ++es)
      Kf[j][es] = __builtin_bit_cast(bf16x8,
          *(const u16x8_t*)(Kb + (kbase + 64 * w + 32 * j + c) * 64 + 16 * es + 8 * hi));

  auto STAGE = [&](int qi, int bb) {
#pragma unroll
    for (int i = 0; i < 4; ++i) {
      int rr = w + 4 * i;
      int ci = rr * 64 + lane;
      int r = ci >> 3, cL = ci & 7;
      glld16(Qb + (qbase0 + qi * 128 + r) * 64 + (cL ^ (r & 7)) * 8, (void*)&Qs[bb][rr * 512]);
    }
  };
  float csum[2] = {0.f, 0.f};
  STAGE(0, 0);
  __syncthreads();
  for (int qi = 0; qi < 8; ++qi) {
    if (qi < 7) STAGE(qi + 1, (qi + 1) & 1);
    const unsigned short* Qt = Qs[qi & 1];
#pragma unroll
    for (int sq = 0; sq < 4; ++sq) {
      bf16x8 A[4];
#pragma unroll
      for (int es = 0; es < 4; ++es)
        A[es] = ldsA(&Qt[sidx(32 * sq + c, 16 * es + 8 * hi)]);
#pragma unroll
      for (int j = 0; j < 2; ++j) {
        f32x16 sv;
#pragma unroll
        for (int i = 0; i < 16; ++i) sv[i] = 0.f;
#pragma unroll
        for (int es = 0; es < 4; ++es) sv = mfma32(A[es], Kf[j][es], sv);
#pragma unroll
        for (int i = 0; i < 16; ++i) csum[j] += expf2(sv[i]);
      }
    }
    __syncthreads();
  }
#pragma unroll
  for (int j = 0; j < 2; ++j) {
    float v = csum[j] + __shfl_xor(csum[j], 32);  // merge hi row-halves
    if (lane < 32)
      Zpart[(kbase + 64 * w + 32 * j + lane) * 4 + qs] = v;
  }
}

// ---------------- Kernel 3: VT[b][h][k] = cv[k]*Qb[k][h], cv fused -------
__global__ __launch_bounds__(256) void vtrans_kernel(
    const unsigned short* __restrict__ Qb, const float* __restrict__ Zpart,
    unsigned short* __restrict__ VT) {
  __shared__ unsigned short T[128 * 72];
  __shared__ float cvs[128];
  const int t = threadIdx.x;
  const int kt = blockIdx.x, b = blockIdx.y;
  const size_t kbase = (size_t)b * SEQ + kt * 128;
#pragma unroll
  for (int it = 0; it < 4; ++it) {  // stage 128x64 tile, chunk-swizzled by r>>3
    int ci = t + 256 * it;
    int r = ci >> 3, ch = ci & 7;
    u16x8_t v = *(const u16x8_t*)(Qb + (kbase + r) * 64 + 8 * ch);
    *(u16x8_t*)(&T[r * 72 + 8 * (ch ^ ((r >> 3) & 7))]) = v;
  }
  if (t < 128) {
    const float* zp = Zpart + (kbase + t) * 4;
    cvs[t] = CSCALE / (zp[0] + zp[1] + zp[2] + zp[3]);
  }
  __syncthreads();
#pragma unroll
  for (int it = 0; it < 4; ++it) {
    int ci = t + 256 * it;
    int h = ci >> 4, c16 = ci & 15;
    u16x8_t o;
#pragma unroll
    for (int j = 0; j < 8; ++j) {
      int r = 8 * c16 + j;
      unsigned short raw = T[r * 72 + 8 * ((h >> 3) ^ (c16 & 7)) + (h & 7)];
      o[j] = f2b(cvs[r] * b2f(raw));
    }
    *(u16x8_t*)(VT + ((size_t)(b * 64 + h)) * SEQ + kt * 128 + 8 * c16) = o;
  }
}

// ---------------- Kernel 4: attention ----------------
// 256 thr (4 waves), 64 q/wave (2 q-blocks) -> 256 q/block. K-frags and
// V-frags each read once per tile and reused across both q-blocks
// (64 FLOP/LDS-byte -> MFMA-bound). k swept in 128-tiles, k-split NS.
// grid 128*NS, XCD-chunked: b = fid&7.
__global__ __launch_bounds__(256) void attn_kernel(
    const unsigned short* __restrict__ Qb, const unsigned short* __restrict__ Kb,
    const unsigned short* __restrict__ VT, float* __restrict__ outp, int nkt) {
  __shared__ unsigned short KV[2][16384];  // [buf][K 8192 | V 8192]
  const int t = threadIdx.x, lane = t & 63, w = t >> 6;
  const int c = lane & 31, hi = lane >> 5;
  const int fid = blockIdx.x;
  const int b = fid & 7, rem = fid >> 3;
  const int qt = rem & 15, ks = rem >> 4;
  const size_t brow = (size_t)b * SEQ;
  const int q0 = qt * 256;
  const int koff = ks * nkt;

  bf16x8 Qf[2][4];  // persistent B-frags: n = own q row (2 q-blocks of 32)
#pragma unroll
  for (int j = 0; j < 2; ++j)
#pragma unroll
    for (int es = 0; es < 4; ++es)
      Qf[j][es] = __builtin_bit_cast(bf16x8,
          *(const u16x8_t*)(Qb + (brow + q0 + 64 * w + 32 * j + c) * 64 + 16 * es + 8 * hi));

  f32x16 acc[2][2];
#pragma unroll
  for (int j = 0; j < 2; ++j)
#pragma unroll
    for (int hb = 0; hb < 2; ++hb)
#pragma unroll
      for (int i = 0; i < 16; ++i) acc[j][hb][i] = 0.f;

  auto STAGE = [&](int tt, int bb) {
    const size_t kb0 = brow + (size_t)(koff + tt) * 128;
#pragma unroll
    for (int i = 0; i < 8; ++i) {
      int rr = w + 4 * i;  // uniform per wave; rr<16: K, else V
      int ci = rr * 64 + lane;
      if (rr < 16) {
        int r = ci >> 3, cL = ci & 7;
        glld16(Kb + (kb0 + r) * 64 + (cL ^ (r & 7)) * 8, (void*)&KV[bb][rr * 512]);
      } else {
        int jj = ci - 1024;
        int h = jj >> 4, cL = jj & 15;
        glld16(VT + ((size_t)(b * 64 + h)) * SEQ + (size_t)(koff + tt) * 128 +
                   (cL ^ (h & 7)) * 8,
               (void*)&KV[bb][rr * 512]);
      }
    }
  };

  auto COMPUTE = [&](int bb) {
    const unsigned short* Ks = &KV[bb][0];
    const unsigned short* Vs = &KV[bb][8192];
#pragma unroll
    for (int kb = 0; kb < 4; ++kb) {
      bf16x8 KA[4];
#pragma unroll
      for (int es = 0; es < 4; ++es)
        KA[es] = ldsA(&Ks[sidx(32 * kb + c, 16 * es + 8 * hi)]);
      bf16x8 fA[2][2];
#pragma unroll
      for (int j = 0; j < 2; ++j) {
        // QK^T swapped: D[k-row][q-col], col = own q
        f32x16 sv;
#pragma unroll
        for (int i = 0; i < 16; ++i) sv[i] = 0.f;
#pragma unroll
        for (int es = 0; es < 4; ++es) sv = mfma32(KA[es], Qf[j][es], sv);
        float p[16];
#pragma unroll
        for (int i = 0; i < 16; ++i) p[i] = expf2(sv[i]);
        unsigned X0 = cvtpk(p[0], p[1]),  X1 = cvtpk(p[2], p[3]);
        unsigned Y0 = cvtpk(p[4], p[5]),  Y1 = cvtpk(p[6], p[7]);
        plane32swap(X0, Y0); plane32swap(X1, Y1);
        u32x4_t F0 = {X0, X1, Y0, Y1};
        unsigned Z0 = cvtpk(p[8], p[9]),   Z1 = cvtpk(p[10], p[11]);
        unsigned W0 = cvtpk(p[12], p[13]), W1 = cvtpk(p[14], p[15]);
        plane32swap(Z0, W0); plane32swap(Z1, W1);
        u32x4_t F1 = {Z0, Z1, W0, W1};
        fA[j][0] = __builtin_bit_cast(bf16x8, F0);
        fA[j][1] = __builtin_bit_cast(bf16x8, F1);
      }
      // PV: acc[j][q][h] += P_j * V'; V-frags shared across j
#pragma unroll
      for (int hb = 0; hb < 2; ++hb) {
        int h = 32 * hb + c;
        int col0 = 32 * kb + 8 * hi;
        bf16x8 VB0 = ldsA(&Vs[h * 128 + (col0 ^ ((h & 7) << 3))]);
        bf16x8 VB1 = ldsA(&Vs[h * 128 + ((col0 + 16) ^ ((h & 7) << 3))]);
        acc[0][hb] = mfma32(fA[0][0], VB0, acc[0][hb]);
        acc[0][hb] = mfma32(fA[0][1], VB1, acc[0][hb]);
        acc[1][hb] = mfma32(fA[1][0], VB0, acc[1][hb]);
        acc[1][hb] = mfma32(fA[1][1], VB1, acc[1][hb]);
      }
    }
  };

  STAGE(0, 0);
  __syncthreads();
  for (int tt = 0; tt < nkt; ++tt) {
    if (tt + 1 < nkt) STAGE(tt + 1, (tt + 1) & 1);
    COMPUTE(tt & 1);
    __syncthreads();
  }
  float* op = outp + (size_t)ks * NROW * 64;
#pragma unroll
  for (int j = 0; j < 2; ++j)
#pragma unroll
    for (int hb = 0; hb < 2; ++hb)
#pragma unroll
      for (int r = 0; r < 16; ++r) {
        int qrow = (r & 3) + 8 * (r >> 2) + 4 * hi;
        op[(brow + q0 + 64 * w + 32 * j + qrow) * 64 + 32 * hb + c] = acc[j][hb][r];
      }
}

// ---------------- Kernel 5: combine 4 k-split partials ----------------
__global__ __launch_bounds__(256) void osum_kernel(
    const float4* __restrict__ A, const float4* __restrict__ B,
    const float4* __restrict__ C, const float4* __restrict__ D,
    float4* __restrict__ O) {
  int i = blockIdx.x * 256 + threadIdx.x;
  float4 x = A[i], y = B[i], z = C[i], u = D[i];
  float4 o;
  o.x = (x.x + y.x) + (z.x + u.x);
  o.y = (x.y + y.y) + (z.y + u.y);
  o.z = (x.z + y.z) + (z.z + u.z);
  o.w = (x.w + y.w) + (z.w + u.w);
  O[i] = o;
}

extern "C" void kernel_launch(void* const* d_in, const int* in_sizes, int n_in,
                              void* d_out, int out_size, void* d_ws, size_t ws_size,
                              hipStream_t stream) {
  const float* X  = (const float*)d_in[0];
  const float* Wq = (const float*)d_in[1];
  const float* Wk = (const float*)d_in[2];
  // d_in[3] (Wv) unused: reference computes v with q_net.
  float* Out = (float*)d_out;

  unsigned char* wsb = (unsigned char*)d_ws;
  const size_t QB_OFF = 0;                    // 4 MB bf16
  const size_t KB_OFF = 4194304;              // 4 MB bf16
  const size_t WB_OFF = 8388608;              // 192 KB bf16
  const size_t Z_OFF  = 8585216;              // 512 KB f32
  const size_t VT_OFF = 9240576;              // 4 MB bf16
  const size_t OP_OFF = 13434880;             // 32 MB f32 (4 partials)
  const size_t TOTAL_SPLIT = OP_OFF + (size_t)4 * NROW * 64 * 4;

  unsigned short* Qb = (unsigned short*)(wsb + QB_OFF);
  unsigned short* Kb = (unsigned short*)(wsb + KB_OFF);
  unsigned short* Wb = (unsigned short*)(wsb + WB_OFF);
  float* Zpart       = (float*)(wsb + Z_OFF);
  unsigned short* VT = (unsigned short*)(wsb + VT_OFF);
  float* Opart       = (float*)(wsb + OP_OFF);

  const bool split = (ws_size >= TOTAL_SPLIT);

  hipLaunchKernelGGL(wcvt_kernel, dim3(48), dim3(256), 0, stream, Wq, Wk, Wb);
  hipLaunchKernelGGL(proj_kernel, dim3(NROW / 64), dim3(256), 0, stream, X, Wb, Qb, Kb);
  hipLaunchKernelGGL(colsum_kernel, dim3(512), dim3(256), 0, stream, Qb, Kb, Zpart);
  hipLaunchKernelGGL(vtrans_kernel, dim3(32, 8), dim3(256), 0, stream, Qb, Zpart, VT);
  if (split) {
    hipLaunchKernelGGL(attn_kernel, dim3(512), dim3(256), 0, stream,
                       Qb, Kb, VT, Opart, 8);
    const size_t PS = (size_t)NROW * 64;
    hipLaunchKernelGGL(osum_kernel, dim3(2048), dim3(256), 0, stream,
                       (const float4*)Opart, (const float4*)(Opart + PS),
                       (const float4*)(Opart + 2 * PS), (const float4*)(Opart + 3 * PS),
                       (float4*)Out);
  } else {
    hipLaunchKernelGGL(attn_kernel, dim3(128), dim3(256), 0, stream,
                       Qb, Kb, VT, Out, 32);
  }
}